// Round 1
// baseline (12049.129 us; speedup 1.0000x reference)
//
#include <hip/hip_runtime.h>
#include <hip/hip_bf16.h>

typedef unsigned short u16;
typedef unsigned int   u32;
typedef __attribute__((ext_vector_type(8))) __bf16 bf16x8;
typedef __attribute__((ext_vector_type(4))) float  f32x4;
typedef __attribute__((ext_vector_type(4))) u32    u32x4;

#define SEQ     512
#define DMODEL  768
#define NHEAD   12
#define DHEAD   64
#define FDIM    3072
#define NLAYER  12
#define NROWS   8192   // B*S

__device__ __forceinline__ u16 f2bf(float f) {
  union { float f; u32 u; } x; x.f = f;
  u32 r = x.u + 0x7fffu + ((x.u >> 16) & 1u);
  return (u16)(r >> 16);
}
__device__ __forceinline__ float u2f(u32 u) { union { u32 u; float f; } x; x.u = u; return x.f; }

// ---------------- weight convert + transpose: in [K][N] f32 -> out [N][K] bf16 (blockIdx.z = layer)
__global__ __launch_bounds__(256) void k_transpose_cvt(const float* __restrict__ in,
                                                       u16* __restrict__ out, int K, int N) {
  __shared__ float tile[32][33];
  size_t off = (size_t)blockIdx.z * K * N;
  in += off; out += off;
  int nb = blockIdx.x * 32, kb = blockIdx.y * 32;
  int tx = threadIdx.x, ty = threadIdx.y;
#pragma unroll
  for (int i = 0; i < 4; i++)
    tile[ty + 8 * i][tx] = in[(size_t)(kb + ty + 8 * i) * N + nb + tx];
  __syncthreads();
#pragma unroll
  for (int i = 0; i < 4; i++)
    out[(size_t)(nb + ty + 8 * i) * K + kb + tx] = f2bf(tile[tx][ty + 8 * i]);
}

// ---------------- embedding gather (f32)
__global__ __launch_bounds__(256) void k_embed(const int* __restrict__ tokens,
                                               const float* __restrict__ emb,
                                               float* __restrict__ x) {
  int idx = blockIdx.x * 256 + threadIdx.x;   // over NROWS * 192 float4 chunks
  int row = idx / 192, c4 = idx % 192;
  int tok = tokens[row];
  reinterpret_cast<float4*>(x + (size_t)row * DMODEL)[c4] =
      reinterpret_cast<const float4*>(emb + (size_t)tok * DMODEL)[c4];
}

// ---------------- T5 relative position bias, TRANSPOSED: pbT[h][k][q]
__global__ __launch_bounds__(256) void k_posbias(const float* __restrict__ rel_bias,
                                                 float* __restrict__ pbT) {
  int idx = blockIdx.x * 256 + threadIdx.x;   // idx = kk*512 + q
  int q = idx & (SEQ - 1), kk = idx >> 9;
  int rel = kk - q;
  int ret = rel > 0 ? 16 : 0;
  int n = rel < 0 ? -rel : rel;
  int b;
  if (n < 8) {
    b = n;
  } else {
    float r = logf((float)n * 0.125f) / 2.772588722239781f * 8.0f;
    int lg = 8 + (int)r;
    b = lg < 15 ? lg : 15;
  }
  b += ret;
#pragma unroll
  for (int h = 0; h < NHEAD; h++)
    pbT[(size_t)h * (SEQ * SEQ) + idx] = rel_bias[b * NHEAD + h];
}

// ---------------- RMSNorm: out = x * rsqrt(mean(x^2)+eps) * w   (bf16 or f32 out)
template <int BF16OUT>
__global__ __launch_bounds__(256) void k_rmsnorm(const float* __restrict__ x,
                                                 const float* __restrict__ w,
                                                 void* __restrict__ out) {
  int row = blockIdx.x, t = threadIdx.x;
  const float* xr = x + (size_t)row * DMODEL;
  float v0 = xr[t], v1 = xr[t + 256], v2 = xr[t + 512];
  float ss = v0 * v0 + v1 * v1 + v2 * v2;
#pragma unroll
  for (int off = 1; off < 64; off <<= 1) ss += __shfl_xor(ss, off);
  __shared__ float part[4];
  if ((t & 63) == 0) part[t >> 6] = ss;
  __syncthreads();
  float tot = part[0] + part[1] + part[2] + part[3];
  float sc = rsqrtf(tot * (1.0f / 768.0f) + 1e-6f);
  if (BF16OUT) {
    u16* o = (u16*)out + (size_t)row * DMODEL;
    o[t]       = f2bf(v0 * sc * w[t]);
    o[t + 256] = f2bf(v1 * sc * w[t + 256]);
    o[t + 512] = f2bf(v2 * sc * w[t + 512]);
  } else {
    float* o = (float*)out + (size_t)row * DMODEL;
    o[t]       = v0 * sc * w[t];
    o[t + 256] = v1 * sc * w[t + 256];
    o[t + 512] = v2 * sc * w[t + 512];
  }
}

// ---------------- async global->LDS, 16B per lane
__device__ __forceinline__ void gload_lds16(const void* g, void* l) {
  __builtin_amdgcn_global_load_lds((const __attribute__((address_space(1))) void*)g,
                                   (__attribute__((address_space(3))) void*)l, 16, 0, 0);
}

// ---------------- bf16 GEMM: C[M,N] = A[M,K] * B[K,N], B given transposed Bt[N,K].
// EPI: 0 = store bf16, 1 = relu -> bf16, 2 = accumulate into f32 (residual add)
template <int EPI>
__global__ __launch_bounds__(256) void k_gemm(const u16* __restrict__ A, const u16* __restrict__ Bt,
                                              u16* __restrict__ outb, float* __restrict__ outf,
                                              int M, int N, int K) {
  __shared__ u16 As[128 * 64];
  __shared__ u16 Bs[128 * 64];
  int tid = threadIdx.x;
  int bn = blockIdx.x * 128, bm = blockIdx.y * 128;
  int lane = tid & 63, wid = tid >> 6;
  int lr = lane & 15, lh = lane >> 4;
  int wm = (wid >> 1) * 64, wn = (wid & 1) * 64;
  int srow = tid >> 3, sseg = tid & 7;

  f32x4 acc[4][4] = {};

  const int nk = K >> 6;
  for (int kt = 0; kt < nk; kt++) {
    int k0 = kt << 6;
#pragma unroll
    for (int c = 0; c < 4; c++) {
      int r = c * 32 + srow;
      gload_lds16(A  + (size_t)(bm + r) * K + k0 + sseg * 8, As + (size_t)tid * 8 + c * 2048);
      gload_lds16(Bt + (size_t)(bn + r) * K + k0 + sseg * 8, Bs + (size_t)tid * 8 + c * 2048);
    }
    asm volatile("s_waitcnt vmcnt(0)" ::: "memory");
    __syncthreads();
#pragma unroll
    for (int kk = 0; kk < 2; kk++) {
      bf16x8 af[4], bfr[4];
#pragma unroll
      for (int m = 0; m < 4; m++)
        af[m] = *reinterpret_cast<const bf16x8*>(As + (wm + m * 16 + lr) * 64 + kk * 32 + lh * 8);
#pragma unroll
      for (int n = 0; n < 4; n++)
        bfr[n] = *reinterpret_cast<const bf16x8*>(Bs + (wn + n * 16 + lr) * 64 + kk * 32 + lh * 8);
#pragma unroll
      for (int m = 0; m < 4; m++)
#pragma unroll
        for (int n = 0; n < 4; n++)
          acc[m][n] = __builtin_amdgcn_mfma_f32_16x16x32_bf16(af[m], bfr[n], acc[m][n], 0, 0, 0);
    }
    __syncthreads();
  }

#pragma unroll
  for (int m = 0; m < 4; m++)
#pragma unroll
    for (int n = 0; n < 4; n++)
#pragma unroll
      for (int r = 0; r < 4; r++) {
        int row = bm + wm + m * 16 + lh * 4 + r;
        int col = bn + wn + n * 16 + lr;
        size_t idx = (size_t)row * N + col;
        float v = acc[m][n][r];
        if (EPI == 0)      outb[idx] = f2bf(v);
        else if (EPI == 1) outb[idx] = f2bf(v > 0.f ? v : 0.f);
        else               outf[idx] += v;
      }
}

// ---------------- attention: one block per (b,h); thread = q-row; two-pass softmax
__global__ __launch_bounds__(512) void k_attn(const u16* __restrict__ qb, const u16* __restrict__ kb,
                                              const u16* __restrict__ vb, const float* __restrict__ pbT,
                                              u16* __restrict__ ob) {
  __shared__ u16 Ks[SEQ * DHEAD];
  __shared__ u16 Vs[SEQ * DHEAD];
  int b = blockIdx.x / NHEAD, h = blockIdx.x % NHEAD;
  int tid = threadIdx.x;
  size_t base = ((size_t)b * SEQ) * DMODEL + h * DHEAD;

#pragma unroll
  for (int i = 0; i < 8; i++) {
    int c = i * 512 + tid;
    int r = c >> 3, sg = c & 7;
    *reinterpret_cast<int4*>(Ks + r * 64 + sg * 8) =
        *reinterpret_cast<const int4*>(kb + base + (size_t)r * DMODEL + sg * 8);
    *reinterpret_cast<int4*>(Vs + r * 64 + sg * 8) =
        *reinterpret_cast<const int4*>(vb + base + (size_t)r * DMODEL + sg * 8);
  }
  __syncthreads();

  int qrow = tid;
  float qr[64];
#pragma unroll
  for (int c = 0; c < 8; c++) {
    u32x4 raw = *reinterpret_cast<const u32x4*>(qb + base + (size_t)qrow * DMODEL + c * 8);
#pragma unroll
    for (int i = 0; i < 4; i++) {
      qr[c * 8 + 2 * i]     = u2f(raw[i] << 16);
      qr[c * 8 + 2 * i + 1] = u2f(raw[i] & 0xffff0000u);
    }
  }
  const float* bias = pbT + (size_t)h * (SEQ * SEQ) + qrow;

  // pass 1: row max
  float mmax = -3.0e38f;
  for (int kk = 0; kk < SEQ; kk++) {
    float d = 0.f;
    const u16* kr = Ks + kk * 64;
#pragma unroll
    for (int c = 0; c < 8; c++) {
      u32x4 raw = *reinterpret_cast<const u32x4*>(kr + c * 8);
#pragma unroll
      for (int i = 0; i < 4; i++) {
        d += qr[c * 8 + 2 * i]     * u2f(raw[i] << 16);
        d += qr[c * 8 + 2 * i + 1] * u2f(raw[i] & 0xffff0000u);
      }
    }
    float sv = d + bias[(size_t)kk * SEQ];
    mmax = fmaxf(mmax, sv);
  }

  // pass 2: exp + PV accumulate
  float l = 0.f;
  float o[64];
#pragma unroll
  for (int j = 0; j < 64; j++) o[j] = 0.f;
  for (int kk = 0; kk < SEQ; kk++) {
    float d = 0.f;
    const u16* kr = Ks + kk * 64;
#pragma unroll
    for (int c = 0; c < 8; c++) {
      u32x4 raw = *reinterpret_cast<const u32x4*>(kr + c * 8);
#pragma unroll
      for (int i = 0; i < 4; i++) {
        d += qr[c * 8 + 2 * i]     * u2f(raw[i] << 16);
        d += qr[c * 8 + 2 * i + 1] * u2f(raw[i] & 0xffff0000u);
      }
    }
    float p = __expf(d + bias[(size_t)kk * SEQ] - mmax);
    l += p;
    const u16* vr = Vs + kk * 64;
#pragma unroll
    for (int c = 0; c < 8; c++) {
      u32x4 raw = *reinterpret_cast<const u32x4*>(vr + c * 8);
#pragma unroll
      for (int i = 0; i < 4; i++) {
        o[c * 8 + 2 * i]     += p * u2f(raw[i] << 16);
        o[c * 8 + 2 * i + 1] += p * u2f(raw[i] & 0xffff0000u);
      }
    }
  }
  float inv = 1.f / l;
#pragma unroll
  for (int j = 0; j < 64; j++)
    ob[base + (size_t)qrow * DMODEL + j] = f2bf(o[j] * inv);
}

extern "C" void kernel_launch(void* const* d_in, const int* in_sizes, int n_in,
                              void* d_out, int out_size, void* d_ws, size_t ws_size,
                              hipStream_t stream) {
  const int*   tokens = (const int*)  d_in[0];
  const float* emb    = (const float*)d_in[1];
  const float* relb   = (const float*)d_in[2];
  const float* ln1w   = (const float*)d_in[3];
  const float* wq     = (const float*)d_in[4];
  const float* wk     = (const float*)d_in[5];
  const float* wv     = (const float*)d_in[6];
  const float* wo     = (const float*)d_in[7];
  const float* ln2w   = (const float*)d_in[8];
  const float* w1     = (const float*)d_in[9];
  const float* w2     = (const float*)d_in[10];
  const float* lnfw   = (const float*)d_in[11];
  float* out = (float*)d_out;

  char* p = (char*)d_ws;
  auto carve = [&](size_t bytes) { char* r = p; p += (bytes + 255) & ~(size_t)255; return r; };
  const size_t DD = (size_t)DMODEL * DMODEL, DF = (size_t)DMODEL * FDIM;

  u16*   wq_t = (u16*)carve(NLAYER * DD * 2);
  u16*   wk_t = (u16*)carve(NLAYER * DD * 2);
  u16*   wv_t = (u16*)carve(NLAYER * DD * 2);
  u16*   wo_t = (u16*)carve(NLAYER * DD * 2);
  u16*   w1_t = (u16*)carve(NLAYER * DF * 2);
  u16*   w2_t = (u16*)carve(NLAYER * DF * 2);
  float* x    = (float*)carve((size_t)NROWS * DMODEL * 4);
  u16*   hbuf = (u16*)carve((size_t)NROWS * DMODEL * 2);
  u16*   qbuf = (u16*)carve((size_t)NROWS * DMODEL * 2);
  u16*   kbuf = (u16*)carve((size_t)NROWS * DMODEL * 2);
  u16*   vbuf = (u16*)carve((size_t)NROWS * DMODEL * 2);
  u16*   abuf = (u16*)carve((size_t)NROWS * DMODEL * 2);
  u16*   fbuf = (u16*)carve((size_t)NROWS * FDIM * 2);
  float* pbT  = (float*)carve((size_t)NHEAD * SEQ * SEQ * 4);

  dim3 tb(32, 8);
  k_transpose_cvt<<<dim3(24, 24, NLAYER), tb, 0, stream>>>(wq, wq_t, DMODEL, DMODEL);
  k_transpose_cvt<<<dim3(24, 24, NLAYER), tb, 0, stream>>>(wk, wk_t, DMODEL, DMODEL);
  k_transpose_cvt<<<dim3(24, 24, NLAYER), tb, 0, stream>>>(wv, wv_t, DMODEL, DMODEL);
  k_transpose_cvt<<<dim3(24, 24, NLAYER), tb, 0, stream>>>(wo, wo_t, DMODEL, DMODEL);
  k_transpose_cvt<<<dim3(96, 24, NLAYER), tb, 0, stream>>>(w1, w1_t, DMODEL, FDIM);
  k_transpose_cvt<<<dim3(24, 96, NLAYER), tb, 0, stream>>>(w2, w2_t, FDIM, DMODEL);

  k_embed<<<NROWS * 192 / 256, 256, 0, stream>>>(tokens, emb, x);
  k_posbias<<<SEQ * SEQ / 256, 256, 0, stream>>>(relb, pbT);

  for (int i = 0; i < NLAYER; i++) {
    k_rmsnorm<1><<<NROWS, 256, 0, stream>>>(x, ln1w + i * DMODEL, hbuf);
    k_gemm<0><<<dim3(6, 64), 256, 0, stream>>>(hbuf, wq_t + (size_t)i * DD, qbuf, nullptr, NROWS, DMODEL, DMODEL);
    k_gemm<0><<<dim3(6, 64), 256, 0, stream>>>(hbuf, wk_t + (size_t)i * DD, kbuf, nullptr, NROWS, DMODEL, DMODEL);
    k_gemm<0><<<dim3(6, 64), 256, 0, stream>>>(hbuf, wv_t + (size_t)i * DD, vbuf, nullptr, NROWS, DMODEL, DMODEL);
    k_attn<<<16 * NHEAD, 512, 0, stream>>>(qbuf, kbuf, vbuf, pbT, abuf);
    k_gemm<2><<<dim3(6, 64), 256, 0, stream>>>(abuf, wo_t + (size_t)i * DD, nullptr, x, NROWS, DMODEL, DMODEL);
    k_rmsnorm<1><<<NROWS, 256, 0, stream>>>(x, ln2w + i * DMODEL, hbuf);
    k_gemm<1><<<dim3(24, 64), 256, 0, stream>>>(hbuf, w1_t + (size_t)i * DF, fbuf, nullptr, NROWS, FDIM, DMODEL);
    k_gemm<2><<<dim3(6, 64), 256, 0, stream>>>(fbuf, w2_t + (size_t)i * DF, nullptr, x, NROWS, DMODEL, FDIM);
  }
  k_rmsnorm<0><<<NROWS, 256, 0, stream>>>(x, lnfw, out);
}

// Round 2
// 4372.282 us; speedup vs baseline: 2.7558x; 2.7558x over previous
//
#include <hip/hip_runtime.h>
#include <hip/hip_bf16.h>

typedef unsigned short u16;
typedef unsigned int   u32;
typedef __attribute__((ext_vector_type(8))) __bf16 bf16x8;
typedef __attribute__((ext_vector_type(4))) float  f32x4;
typedef __attribute__((ext_vector_type(4))) u32    u32x4;

#define SEQ     512
#define DMODEL  768
#define NHEAD   12
#define DHEAD   64
#define FDIM    3072
#define NLAYER  12
#define NROWS   8192   // B*S
#define QKVN    2304   // 3*DMODEL

__device__ __forceinline__ u16 f2bf(float f) {
  union { float f; u32 u; } x; x.f = f;
  u32 r = x.u + 0x7fffu + ((x.u >> 16) & 1u);
  return (u16)(r >> 16);
}
__device__ __forceinline__ float u2f(u32 u) { union { u32 u; float f; } x; x.u = u; return x.f; }

// ---------------- weight convert + transpose: in [K][N] f32 -> out [N][K] bf16 (blockIdx.z = layer)
__global__ __launch_bounds__(256) void k_transpose_cvt(const float* __restrict__ in,
                                                       u16* __restrict__ out, int K, int N,
                                                       size_t istride, size_t ostride) {
  __shared__ float tile[32][33];
  in  += (size_t)blockIdx.z * istride;
  out += (size_t)blockIdx.z * ostride;
  int nb = blockIdx.x * 32, kb = blockIdx.y * 32;
  int tx = threadIdx.x, ty = threadIdx.y;
#pragma unroll
  for (int i = 0; i < 4; i++)
    tile[ty + 8 * i][tx] = in[(size_t)(kb + ty + 8 * i) * N + nb + tx];
  __syncthreads();
#pragma unroll
  for (int i = 0; i < 4; i++)
    out[(size_t)(nb + ty + 8 * i) * K + kb + tx] = f2bf(tile[tx][ty + 8 * i]);
}

// ---------------- embedding gather (f32)
__global__ __launch_bounds__(256) void k_embed(const int* __restrict__ tokens,
                                               const float* __restrict__ emb,
                                               float* __restrict__ x) {
  int idx = blockIdx.x * 256 + threadIdx.x;
  int row = idx / 192, c4 = idx % 192;
  int tok = tokens[row];
  reinterpret_cast<float4*>(x + (size_t)row * DMODEL)[c4] =
      reinterpret_cast<const float4*>(emb + (size_t)tok * DMODEL)[c4];
}

// ---------------- T5 relative position bias: pb[h][q][k]
__global__ __launch_bounds__(256) void k_posbias(const float* __restrict__ rel_bias,
                                                 float* __restrict__ pb) {
  int idx = blockIdx.x * 256 + threadIdx.x;   // idx = q*512 + k
  int kk = idx & (SEQ - 1), q = idx >> 9;
  int rel = kk - q;
  int ret = rel > 0 ? 16 : 0;
  int n = rel < 0 ? -rel : rel;
  int b;
  if (n < 8) {
    b = n;
  } else {
    float r = logf((float)n * 0.125f) / 2.772588722239781f * 8.0f;
    int lg = 8 + (int)r;
    b = lg < 15 ? lg : 15;
  }
  b += ret;
#pragma unroll
  for (int h = 0; h < NHEAD; h++)
    pb[(size_t)h * (SEQ * SEQ) + idx] = rel_bias[b * NHEAD + h];
}

// ---------------- RMSNorm: out = x * rsqrt(mean(x^2)+eps) * w
template <int BF16OUT>
__global__ __launch_bounds__(256) void k_rmsnorm(const float* __restrict__ x,
                                                 const float* __restrict__ w,
                                                 void* __restrict__ out) {
  int row = blockIdx.x, t = threadIdx.x;
  const float* xr = x + (size_t)row * DMODEL;
  float v0 = xr[t], v1 = xr[t + 256], v2 = xr[t + 512];
  float ss = v0 * v0 + v1 * v1 + v2 * v2;
#pragma unroll
  for (int off = 1; off < 64; off <<= 1) ss += __shfl_xor(ss, off);
  __shared__ float part[4];
  if ((t & 63) == 0) part[t >> 6] = ss;
  __syncthreads();
  float tot = part[0] + part[1] + part[2] + part[3];
  float sc = rsqrtf(tot * (1.0f / 768.0f) + 1e-6f);
  if (BF16OUT) {
    u16* o = (u16*)out + (size_t)row * DMODEL;
    o[t]       = f2bf(v0 * sc * w[t]);
    o[t + 256] = f2bf(v1 * sc * w[t + 256]);
    o[t + 512] = f2bf(v2 * sc * w[t + 512]);
  } else {
    float* o = (float*)out + (size_t)row * DMODEL;
    o[t]       = v0 * sc * w[t];
    o[t + 256] = v1 * sc * w[t + 256];
    o[t + 512] = v2 * sc * w[t + 512];
  }
}

// ---------------- async global->LDS, 16B per lane
__device__ __forceinline__ void gload_lds16(const void* g, void* l) {
  __builtin_amdgcn_global_load_lds((const __attribute__((address_space(1))) void*)g,
                                   (__attribute__((address_space(3))) void*)l, 16, 0, 0);
}

// ---------------- bf16 GEMM: C[M,N] = A[M,K] * Bt[N,K]^T
// EPI: 0 = store bf16, 1 = relu -> bf16, 2 = accumulate into f32 (residual add)
template <int EPI>
__global__ __launch_bounds__(256) void k_gemm(const u16* __restrict__ A, const u16* __restrict__ Bt,
                                              u16* __restrict__ outb, float* __restrict__ outf,
                                              int M, int N, int K) {
  __shared__ u16 As[128 * 64];
  __shared__ u16 Bs[128 * 64];
  int tid = threadIdx.x;
  int bn = blockIdx.x * 128, bm = blockIdx.y * 128;
  int lane = tid & 63, wid = tid >> 6;
  int lr = lane & 15, lh = lane >> 4;
  int wm = (wid >> 1) * 64, wn = (wid & 1) * 64;
  int srow = tid >> 3, sseg = tid & 7;

  f32x4 acc[4][4] = {};

  const int nk = K >> 6;
  for (int kt = 0; kt < nk; kt++) {
    int k0 = kt << 6;
#pragma unroll
    for (int c = 0; c < 4; c++) {
      int r = c * 32 + srow;
      gload_lds16(A  + (size_t)(bm + r) * K + k0 + sseg * 8, As + (size_t)tid * 8 + c * 2048);
      gload_lds16(Bt + (size_t)(bn + r) * K + k0 + sseg * 8, Bs + (size_t)tid * 8 + c * 2048);
    }
    asm volatile("s_waitcnt vmcnt(0)" ::: "memory");
    __syncthreads();
#pragma unroll
    for (int kk = 0; kk < 2; kk++) {
      bf16x8 af[4], bfr[4];
#pragma unroll
      for (int m = 0; m < 4; m++)
        af[m] = *reinterpret_cast<const bf16x8*>(As + (wm + m * 16 + lr) * 64 + kk * 32 + lh * 8);
#pragma unroll
      for (int n = 0; n < 4; n++)
        bfr[n] = *reinterpret_cast<const bf16x8*>(Bs + (wn + n * 16 + lr) * 64 + kk * 32 + lh * 8);
#pragma unroll
      for (int m = 0; m < 4; m++)
#pragma unroll
        for (int n = 0; n < 4; n++)
          acc[m][n] = __builtin_amdgcn_mfma_f32_16x16x32_bf16(af[m], bfr[n], acc[m][n], 0, 0, 0);
    }
    __syncthreads();
  }

#pragma unroll
  for (int m = 0; m < 4; m++)
#pragma unroll
    for (int n = 0; n < 4; n++)
#pragma unroll
      for (int r = 0; r < 4; r++) {
        int row = bm + wm + m * 16 + lh * 4 + r;
        int col = bn + wn + n * 16 + lr;
        size_t idx = (size_t)row * N + col;
        float v = acc[m][n][r];
        if (EPI == 0)      outb[idx] = f2bf(v);
        else if (EPI == 1) outb[idx] = f2bf(v > 0.f ? v : 0.f);
        else               outf[idx] += v;
      }
}

// ---------------- V transpose per (b,h): qkv V-section [S][64] -> vt[bh][64][S] bf16
__global__ __launch_bounds__(256) void k_vtrans(const u16* __restrict__ qkv, u16* __restrict__ vt) {
  __shared__ u16 t[32][33];
  int bh = blockIdx.z;
  int b = bh / NHEAD, h = bh % NHEAD;
  int d0 = blockIdx.x * 32, s0 = blockIdx.y * 32;
  int tx = threadIdx.x, ty = threadIdx.y;
  const u16* src = qkv + (size_t)(b * SEQ + s0) * QKVN + 2 * DMODEL + h * DHEAD + d0;
#pragma unroll
  for (int i = 0; i < 4; i++)
    t[ty + 8 * i][tx] = src[(size_t)(ty + 8 * i) * QKVN + tx];   // t[s][d]
  __syncthreads();
  u16* dst = vt + ((size_t)bh * DHEAD + d0) * SEQ + s0;
#pragma unroll
  for (int i = 0; i < 4; i++)
    dst[(size_t)(ty + 8 * i) * SEQ + tx] = t[tx][ty + 8 * i];
}

// ---------------- MFMA flash attention: block = (b,h) x 128-row Q tile, 4 waves x 32 rows
__global__ __launch_bounds__(256) void k_attn(const u16* __restrict__ qkv,
                                              const u16* __restrict__ vt,
                                              const float* __restrict__ pb,
                                              u16* __restrict__ ob) {
  __shared__ u16 Ks[32 * 64];       // [kv][d], 16B chunks XOR-swizzled: c ^= (row&7)
  __shared__ u16 Vs[64 * 32];       // [d][kv], 16B chunks XOR-swizzled: c ^= (d&3)^((d>>2)&3)
  __shared__ u16 Ps[4][32 * 40];    // per-wave P tile, row stride 40 u16
  int b = blockIdx.x / NHEAD, h = blockIdx.x % NHEAD;
  int qt = blockIdx.y;
  int tid = threadIdx.x;
  int lane = tid & 63, wid = tid >> 6;
  int lr = lane & 15, lh = lane >> 4;
  int q0 = qt * 128 + wid * 32;

  // Q fragments (held in registers for the whole kernel)
  bf16x8 aq[2][2];
#pragma unroll
  for (int m = 0; m < 2; m++) {
    const u16* qp = qkv + (size_t)(b * SEQ + q0 + m * 16 + lr) * QKVN + h * DHEAD;
#pragma unroll
    for (int kk = 0; kk < 2; kk++)
      aq[m][kk] = *reinterpret_cast<const bf16x8*>(qp + kk * 32 + lh * 8);
  }

  float mrun[2][4], lrun[2][4];
  f32x4 acc_o[2][4] = {};
#pragma unroll
  for (int m = 0; m < 2; m++)
#pragma unroll
    for (int r = 0; r < 4; r++) { mrun[m][r] = -3.0e38f; lrun[m][r] = 0.f; }

  // staging source addresses (swizzle applied on global source; LDS dest linear)
  int krow = tid >> 3, kc = tid & 7;
  const u16* ksrc = qkv + (size_t)(b * SEQ + krow) * QKVN + DMODEL + h * DHEAD + ((kc ^ (krow & 7)) * 8);
  int vd = tid >> 2, vc = tid & 3;
  int vch = vc ^ (vd & 3) ^ ((vd >> 2) & 3);
  const u16* vsrc = vt + ((size_t)blockIdx.x * DHEAD + vd) * SEQ + vch * 8;

  const float* bias = pb + (size_t)h * (SEQ * SEQ);

  for (int kt = 0; kt < 16; kt++) {
    int kv0 = kt * 32;
    __syncthreads();
    gload_lds16(ksrc + (size_t)kv0 * QKVN, Ks + (size_t)tid * 8);
    gload_lds16(vsrc + kv0, Vs + (size_t)tid * 8);
    asm volatile("s_waitcnt vmcnt(0)" ::: "memory");
    __syncthreads();

    // S = Q K^T   (col = kv = n*16+lr, row = q = lh*4+r)
    f32x4 sc[2][2] = {};
#pragma unroll
    for (int kk = 0; kk < 2; kk++) {
      bf16x8 bk[2];
#pragma unroll
      for (int n = 0; n < 2; n++) {
        int row = n * 16 + lr;
        int ch = (kk * 4 + lh) ^ (row & 7);
        bk[n] = *reinterpret_cast<const bf16x8*>(Ks + row * 64 + ch * 8);
      }
#pragma unroll
      for (int m = 0; m < 2; m++)
#pragma unroll
        for (int n = 0; n < 2; n++)
          sc[m][n] = __builtin_amdgcn_mfma_f32_16x16x32_bf16(aq[m][kk], bk[n], sc[m][n], 0, 0, 0);
    }
    // V fragments for PV (read now so LDS reads overlap softmax VALU)
    bf16x8 bv[4];
#pragma unroll
    for (int n = 0; n < 4; n++) {
      int d = n * 16 + lr;
      int ch = lh ^ (d & 3) ^ ((d >> 2) & 3);
      bv[n] = *reinterpret_cast<const bf16x8*>(Vs + d * 32 + ch * 8);
    }
    // + bias
#pragma unroll
    for (int m = 0; m < 2; m++) {
      const float* bp = bias + (size_t)(q0 + m * 16 + lh * 4) * SEQ + kv0 + lr;
#pragma unroll
      for (int n = 0; n < 2; n++)
#pragma unroll
        for (int r = 0; r < 4; r++)
          sc[m][n][r] += bp[(size_t)r * SEQ + n * 16];
    }
    // online softmax (row reduction = shfl over the 16-lane lr group)
    u16* pw = Ps[wid];
#pragma unroll
    for (int m = 0; m < 2; m++) {
#pragma unroll
      for (int r = 0; r < 4; r++) {
        float v = fmaxf(sc[m][0][r], sc[m][1][r]);
        v = fmaxf(v, __shfl_xor(v, 1));
        v = fmaxf(v, __shfl_xor(v, 2));
        v = fmaxf(v, __shfl_xor(v, 4));
        v = fmaxf(v, __shfl_xor(v, 8));
        float mold = mrun[m][r];
        float mn = fmaxf(mold, v);
        float corr = __expf(mold - mn);
        mrun[m][r] = mn;
        float p0 = __expf(sc[m][0][r] - mn);
        float p1 = __expf(sc[m][1][r] - mn);
        float ps = p0 + p1;
        ps += __shfl_xor(ps, 1);
        ps += __shfl_xor(ps, 2);
        ps += __shfl_xor(ps, 4);
        ps += __shfl_xor(ps, 8);
        lrun[m][r] = lrun[m][r] * corr + ps;
        pw[(m * 16 + lh * 4 + r) * 40 + lr]      = f2bf(p0);
        pw[(m * 16 + lh * 4 + r) * 40 + 16 + lr] = f2bf(p1);
#pragma unroll
        for (int n = 0; n < 4; n++)
          acc_o[m][n][r] *= corr;
      }
    }
    // O += P V   (A-frag = P from per-wave LDS tile)
#pragma unroll
    for (int m = 0; m < 2; m++) {
      bf16x8 ap = *reinterpret_cast<const bf16x8*>(Ps[wid] + (m * 16 + lr) * 40 + lh * 8);
#pragma unroll
      for (int n = 0; n < 4; n++)
        acc_o[m][n] = __builtin_amdgcn_mfma_f32_16x16x32_bf16(ap, bv[n], acc_o[m][n], 0, 0, 0);
    }
  }

  // epilogue: normalize and store bf16
#pragma unroll
  for (int m = 0; m < 2; m++)
#pragma unroll
    for (int r = 0; r < 4; r++) {
      float inv = 1.f / lrun[m][r];
      size_t orow = (size_t)(b * SEQ + q0 + m * 16 + lh * 4 + r);
#pragma unroll
      for (int n = 0; n < 4; n++)
        ob[orow * DMODEL + h * DHEAD + n * 16 + lr] = f2bf(acc_o[m][n][r] * inv);
    }
}

extern "C" void kernel_launch(void* const* d_in, const int* in_sizes, int n_in,
                              void* d_out, int out_size, void* d_ws, size_t ws_size,
                              hipStream_t stream) {
  const int*   tokens = (const int*)  d_in[0];
  const float* emb    = (const float*)d_in[1];
  const float* relb   = (const float*)d_in[2];
  const float* ln1w   = (const float*)d_in[3];
  const float* wq     = (const float*)d_in[4];
  const float* wk     = (const float*)d_in[5];
  const float* wv     = (const float*)d_in[6];
  const float* wo     = (const float*)d_in[7];
  const float* ln2w   = (const float*)d_in[8];
  const float* w1     = (const float*)d_in[9];
  const float* w2     = (const float*)d_in[10];
  const float* lnfw   = (const float*)d_in[11];
  float* out = (float*)d_out;

  char* p = (char*)d_ws;
  auto carve = [&](size_t bytes) { char* r = p; p += (bytes + 255) & ~(size_t)255; return r; };
  const size_t DD = (size_t)DMODEL * DMODEL, DF = (size_t)DMODEL * FDIM;

  u16*   wqkv_t = (u16*)carve(NLAYER * 3 * DD * 2);
  u16*   wo_t   = (u16*)carve(NLAYER * DD * 2);
  u16*   w1_t   = (u16*)carve(NLAYER * DF * 2);
  u16*   w2_t   = (u16*)carve(NLAYER * DF * 2);
  float* x      = (float*)carve((size_t)NROWS * DMODEL * 4);
  u16*   hbuf   = (u16*)carve((size_t)NROWS * DMODEL * 2);
  u16*   qkvbuf = (u16*)carve((size_t)NROWS * QKVN * 2);
  u16*   abuf   = (u16*)carve((size_t)NROWS * DMODEL * 2);
  u16*   fbuf   = (u16*)carve((size_t)NROWS * FDIM * 2);
  float* pb     = (float*)carve((size_t)NHEAD * SEQ * SEQ * 4);
  u16*   vtbuf  = fbuf;   // overlay: vt dead before ffn1 writes fbuf

  dim3 tb(32, 8);
  k_transpose_cvt<<<dim3(24, 24, NLAYER), tb, 0, stream>>>(wq, wqkv_t,            DMODEL, DMODEL, DD, 3 * DD);
  k_transpose_cvt<<<dim3(24, 24, NLAYER), tb, 0, stream>>>(wk, wqkv_t + DD,       DMODEL, DMODEL, DD, 3 * DD);
  k_transpose_cvt<<<dim3(24, 24, NLAYER), tb, 0, stream>>>(wv, wqkv_t + 2 * DD,   DMODEL, DMODEL, DD, 3 * DD);
  k_transpose_cvt<<<dim3(24, 24, NLAYER), tb, 0, stream>>>(wo, wo_t,              DMODEL, DMODEL, DD, DD);
  k_transpose_cvt<<<dim3(96, 24, NLAYER), tb, 0, stream>>>(w1, w1_t,              DMODEL, FDIM,   DF, DF);
  k_transpose_cvt<<<dim3(24, 96, NLAYER), tb, 0, stream>>>(w2, w2_t,              FDIM, DMODEL,   DF, DF);

  k_embed<<<NROWS * 192 / 256, 256, 0, stream>>>(tokens, emb, x);
  k_posbias<<<SEQ * SEQ / 256, 256, 0, stream>>>(relb, pb);

  for (int i = 0; i < NLAYER; i++) {
    k_rmsnorm<1><<<NROWS, 256, 0, stream>>>(x, ln1w + i * DMODEL, hbuf);
    k_gemm<0><<<dim3(18, 64), 256, 0, stream>>>(hbuf, wqkv_t + (size_t)i * 3 * DD, qkvbuf, nullptr, NROWS, QKVN, DMODEL);
    k_vtrans<<<dim3(2, 16, 192), tb, 0, stream>>>(qkvbuf, vtbuf);
    k_attn<<<dim3(192, 4), 256, 0, stream>>>(qkvbuf, vtbuf, pb, abuf);
    k_gemm<2><<<dim3(6, 64), 256, 0, stream>>>(abuf, wo_t + (size_t)i * DD, nullptr, x, NROWS, DMODEL, DMODEL);
    k_rmsnorm<1><<<NROWS, 256, 0, stream>>>(x, ln2w + i * DMODEL, hbuf);
    k_gemm<1><<<dim3(24, 64), 256, 0, stream>>>(hbuf, w1_t + (size_t)i * DF, fbuf, nullptr, NROWS, FDIM, DMODEL);
    k_gemm<2><<<dim3(6, 64), 256, 0, stream>>>(fbuf, w2_t + (size_t)i * DF, nullptr, x, NROWS, DMODEL, FDIM);
  }
  k_rmsnorm<0><<<NROWS, 256, 0, stream>>>(x, lnfw, out);
}